// Round 6
// baseline (1884.750 us; speedup 1.0000x reference)
//
#include <hip/hip_runtime.h>
#include <math.h>

// ---------------------------------------------------------------------------
// overAll_37606733644133 : relational GNN (2-layer Householder-reflection
// message passing with edge softmax) + proxy attention + gated mixing.
//
// Round-6: k_pg rewritten as BARRIER-FREE wave-autonomous MFMA:
//  - each wave owns 16 nodes end-to-end (logits vs all 64 proxies ->
//    in-register softmax -> att transpose via per-wave LDS scratch ->
//    pacc -> per-ks pf build (scratch transpose + fp32 o re-read) ->
//    gate GEMM -> epilogue with pacc recompute). ZERO __syncthreads.
//  - LDS 26.6KB/block (per-wave scratch only); occupancy VGPR-limited.
//  - A-fragments are lane-private (row c, cols 32ks+8kg+j) -> no sharing.
//  - keeps: fp16 gather path, fused-dual k_layer, g_ew table, hier. scan.
// ---------------------------------------------------------------------------

#define NN    50000
#define NE    800000
#define NR    2000
#define FF    128
#define FDIM  384
#define OD    768     // output row stride (2 duals x 384)
#define PP    64
#define NEPS  1e-12f
#define NBLK  49      // scan blocks: ceil(50000/1024)
#define SCRW  68      // att scratch row stride (u32)
#define TSTR  36      // pacc-transpose scratch row stride (f32)

typedef unsigned int u32;
typedef unsigned short u16;
typedef __attribute__((ext_vector_type(8))) short bf16x8;     // 8 bf16 (4 VGPRs)
typedef __attribute__((ext_vector_type(8))) _Float16 f16x8;   // 8 fp16 (4 VGPRs)
typedef __attribute__((ext_vector_type(4))) float f32x4;

// ---- static device scratch ------------------------------------------------
__device__ int   g_rowptr[NN + 1];
__device__ int   g_cnt[NN];
__device__ int   g_bsum[64];
__device__ u32   g_csr[NE];               // (src<<16) | rel
__device__ float g_relnorm[NR * FF];
__device__ float2 g_ew[2 * NR];           // [layer][r] = (exp(atab_ent), exp(atab_rel))
// fp16 gather slabs: [slab][n][0..128)=ent feats, [128..256)=rel feats
__device__ __attribute__((aligned(16))) _Float16 g_hh[2][NN][256];   // 51.2 MB
__device__ __attribute__((aligned(16))) _Float16 g_ent16[NN * FF];   // 12.8 MB
// split-bf16 B-operands, all n-major / k-contiguous:
__device__ __attribute__((aligned(16))) u16 g_wt_hi[2 * FDIM * FDIM];  // [d][f][k] = W_d[k][f]
__device__ __attribute__((aligned(16))) u16 g_wt_lo[2 * FDIM * FDIM];
__device__ __attribute__((aligned(16))) u16 g_pxn_hi[2 * PP * FDIM];   // [d][p][k] = l2n(proxy_d[p])[k]
__device__ __attribute__((aligned(16))) u16 g_pxn_lo[2 * PP * FDIM];
__device__ __attribute__((aligned(16))) u16 g_pxT_hi[2 * FDIM * PP];   // [d][f][p] = proxy_d[p][f]
__device__ __attribute__((aligned(16))) u16 g_pxT_lo[2 * FDIM * PP];

__device__ __forceinline__ float wsum64(float v) {
#pragma unroll
    for (int m = 32; m > 0; m >>= 1) v += __shfl_xor(v, m, 64);
    return v;
}
// 16-lane-group sum (masks 1,2,4,8), two values interleaved
__device__ __forceinline__ void red16x2(float& a, float& b) {
#pragma unroll
    for (int m = 1; m < 16; m <<= 1) {
        float ta = __shfl_xor(a, m, 64);
        float tb = __shfl_xor(b, m, 64);
        a += ta; b += tb;
    }
}

// fp32 -> (bf16_hi << 16) | bf16_lo, both RNE; hi+lo reconstructs to ~2^-16 rel
__device__ __forceinline__ u32 pack_bf(float f) {
    u32 x = __float_as_uint(f);
    u32 hr = (x + 0x7FFFu + ((x >> 16) & 1u)) & 0xFFFF0000u;
    float res = f - __uint_as_float(hr);
    u32 y = __float_as_uint(res);
    u32 lr = (y + 0x7FFFu + ((y >> 16) & 1u)) >> 16;
    return hr | lr;
}
__device__ __forceinline__ float unpack_bf(u32 pk) {
    return __uint_as_float(pk & 0xFFFF0000u) + __uint_as_float(pk << 16);
}

// split 8 packed u32 (hi|lo) -> hi / lo bf16x8 fragments
__device__ __forceinline__ void split_frag(const u32 q[8], bf16x8& ah, bf16x8& al) {
    union { u32 u[4]; bf16x8 v; } H, L;
#pragma unroll
    for (int j = 0; j < 4; j++) {
        H.u[j] = __builtin_amdgcn_perm(q[2 * j + 1], q[2 * j], 0x07060302u);
        L.u[j] = __builtin_amdgcn_perm(q[2 * j + 1], q[2 * j], 0x05040100u);
    }
    ah = H.v; al = L.v;
}
// read 8 packed elems (32B, 2x b128) -> hi / lo bf16x8 fragments
__device__ __forceinline__ void load_afrag(const u32* p, bf16x8& ah, bf16x8& al) {
    u32 q[8];
    *reinterpret_cast<float4*>(q)     = *reinterpret_cast<const float4*>(p);
    *reinterpret_cast<float4*>(q + 4) = *reinterpret_cast<const float4*>(p + 4);
    split_frag(q, ah, al);
}

__global__ __launch_bounds__(256) void k_zero() {
    int i = blockIdx.x * 256 + threadIdx.x;
    if (i < NN) g_cnt[i] = 0;
}

// --- relnorm[r] = l2norm(rel_emb[r]); g_ew[l][r] = exp(relnorm.attn) both duals ---
__global__ __launch_bounds__(256) void k_prep_rel(
    const float* __restrict__ rel_emb, const float* __restrict__ attn_e,
    const float* __restrict__ attn_r) {
    int wave = threadIdx.x >> 6, lane = threadIdx.x & 63;
    int r = blockIdx.x * 4 + wave;
    if (r >= NR) return;
    float2 v = *(const float2*)(rel_emb + r * FF + 2 * lane);
    float ss = wsum64(v.x * v.x + v.y * v.y);
    float inv = 1.f / fmaxf(sqrtf(ss), NEPS);
    float rn0 = v.x * inv, rn1 = v.y * inv;
    *(float2*)(g_relnorm + r * FF + 2 * lane) = make_float2(rn0, rn1);
#pragma unroll
    for (int t = 0; t < 4; t++) {   // t = dual*2 + layer
        const float* av = ((t < 2) ? attn_e : attn_r) + (t & 1) * FF + 2 * lane;
        float d = wsum64(rn0 * av[0] + rn1 * av[1]);
        if (lane == 0) ((float*)&g_ew[(t & 1) * NR + r])[t >> 1] = expf(d);
    }
}

// --- ent_emb -> fp16 table for the k_init gather ---
__global__ __launch_bounds__(256) void k_prep_ent(const float* __restrict__ ent_emb) {
    int i = (blockIdx.x * 256 + threadIdx.x) * 8;
    if (i >= NN * FF) return;
    float4 a = *(const float4*)(ent_emb + i);
    float4 b = *(const float4*)(ent_emb + i + 4);
    f16x8 h;
    h[0] = (_Float16)a.x; h[1] = (_Float16)a.y; h[2] = (_Float16)a.z; h[3] = (_Float16)a.w;
    h[4] = (_Float16)b.x; h[5] = (_Float16)b.y; h[6] = (_Float16)b.z; h[7] = (_Float16)b.w;
    *(f16x8*)(g_ent16 + i) = h;
}

// --- split-bf16 proxy tables: l2n rows ([d][p][k]) and raw transpose ([d][f][p]) ---
__global__ __launch_bounds__(256) void k_prep_proxy(
    const float* __restrict__ proxy_e, const float* __restrict__ proxy_r) {
    int wave = threadIdx.x >> 6, lane = threadIdx.x & 63;
    int row = blockIdx.x * 4 + wave;  // 0..127
    if (row >= 2 * PP) return;
    int d = row >> 6, p = row & 63;
    const float* pr = ((d == 0) ? proxy_e : proxy_r) + p * FDIM;
    float v[6];
    float ss = 0.f;
#pragma unroll
    for (int j = 0; j < 6; j++) {
        v[j] = pr[lane + 64 * j];
        ss += v[j] * v[j];
    }
    ss = wsum64(ss);
    float inv = 1.f / fmaxf(sqrtf(ss), NEPS);
#pragma unroll
    for (int j = 0; j < 6; j++) {
        int k = lane + 64 * j;
        u32 pn = pack_bf(v[j] * inv);
        g_pxn_hi[(d * PP + p) * FDIM + k] = (u16)(pn >> 16);
        g_pxn_lo[(d * PP + p) * FDIM + k] = (u16)(pn & 0xFFFFu);
        u32 pt = pack_bf(v[j]);
        g_pxT_hi[(d * FDIM + k) * PP + p] = (u16)(pt >> 16);
        g_pxT_lo[(d * FDIM + k) * PP + p] = (u16)(pt & 0xFFFFu);
    }
}

// --- split-bf16 gate weights, transposed: wt[d][f][k] = W_d[k][f] ---
__global__ __launch_bounds__(256) void k_prep_wt(
    const float* __restrict__ gate_e, const float* __restrict__ gate_r) {
    int idx = blockIdx.x * 256 + threadIdx.x;
    if (idx >= 2 * FDIM * FDIM) return;
    int d = idx / (FDIM * FDIM);
    int rem = idx - d * (FDIM * FDIM);
    int k = rem / FDIM;
    int f = rem - k * FDIM;          // consecutive lanes -> consecutive f: coalesced read
    float wv = (d ? gate_r : gate_e)[k * FDIM + f];
    u32 pk = pack_bf(wv);
    g_wt_hi[(d * FDIM + f) * FDIM + k] = (u16)(pk >> 16);
    g_wt_lo[(d * FDIM + f) * FDIM + k] = (u16)(pk & 0xFFFFu);
}

__global__ __launch_bounds__(256) void k_count(const int* __restrict__ dst) {
    int e = blockIdx.x * 256 + threadIdx.x;
    if (e < NE) atomicAdd(&g_cnt[dst[e]], 1);
}

// --- hierarchical exclusive scan: per-block scan -> block-sum scan -> add ---
__global__ __launch_bounds__(1024) void k_scan1() {
    __shared__ int s[1024];
    int b = blockIdx.x, tid = threadIdx.x;
    int i = b * 1024 + tid;
    int v = (i < NN) ? g_cnt[i] : 0;
    s[tid] = v;
    __syncthreads();
    for (int off = 1; off < 1024; off <<= 1) {
        int t = (tid >= off) ? s[tid - off] : 0;
        __syncthreads();
        s[tid] += t;
        __syncthreads();
    }
    if (i < NN) {
        g_rowptr[i] = s[tid] - v;   // exclusive within block
        g_cnt[i] = 0;
    }
    if (tid == 1023) g_bsum[b] = s[1023];
}
__global__ __launch_bounds__(64) void k_scan2() {
    int lane = threadIdx.x;
    int v = (lane < NBLK) ? g_bsum[lane] : 0;
#pragma unroll
    for (int off = 1; off < 64; off <<= 1) {
        int t = __shfl_up(v, off, 64);
        if (lane >= off) v += t;
    }
    if (lane < NBLK) g_bsum[lane] = v;  // inclusive block-sum scan
    if (lane == 0) g_rowptr[NN] = NE;
}
__global__ __launch_bounds__(1024) void k_scan3() {
    int b = blockIdx.x;
    if (b == 0) return;
    int i = b * 1024 + threadIdx.x;
    if (i < NN) g_rowptr[i] += g_bsum[b - 1];
}

__global__ __launch_bounds__(256) void k_fill(
    const int* __restrict__ src, const int* __restrict__ dst,
    const int* __restrict__ rel) {
    int e = blockIdx.x * 256 + threadIdx.x;
    if (e >= NE) return;
    int d = dst[e];
    int pos = atomicAdd(&g_cnt[d], 1);
    g_csr[g_rowptr[d] + pos] = ((u32)src[e] << 16) | (u32)rel[e];
}

// --- initial features: tanh(mean over incoming edges), both duals ---
// 4 edges/wave (16-lane groups), 8 features/lane; ent gathered fp16.
__global__ __launch_bounds__(256) void k_init(
    const float* __restrict__ rel_emb, float* __restrict__ out) {
    int wave = threadIdx.x >> 6, lane = threadIdx.x & 63;
    int n = blockIdx.x * 4 + wave;
    if (n >= NN) return;
    int g16 = lane >> 4, li = lane & 15;
    int s0 = g_rowptr[n], s1 = g_rowptr[n + 1];
    float ae[8], ar[8];
#pragma unroll
    for (int i = 0; i < 8; i++) { ae[i] = 0.f; ar[i] = 0.f; }
    for (int idx = s0; idx < s1; idx += 4) {
        int e = idx + g16;
        if (e < s1) {
            u32 pk = g_csr[e];
            int s = (int)(pk >> 16), r = (int)(pk & 0xFFFFu);
            f16x8 ev = *(const f16x8*)(g_ent16 + (size_t)s * FF + 8 * li);
            const float* rp = rel_emb + (size_t)r * FF + 8 * li;
            float4 r0 = *(const float4*)rp, r1 = *(const float4*)(rp + 4);
            float rv[8] = {r0.x, r0.y, r0.z, r0.w, r1.x, r1.y, r1.z, r1.w};
#pragma unroll
            for (int i = 0; i < 8; i++) {
                ae[i] += (float)ev[i];
                ar[i] += rv[i];
            }
        }
    }
#pragma unroll
    for (int mk = 16; mk < 64; mk <<= 1)
#pragma unroll
        for (int i = 0; i < 8; i++) {
            ae[i] += __shfl_xor(ae[i], mk, 64);
            ar[i] += __shfl_xor(ar[i], mk, 64);
        }
    float invd = 1.f / (float)max(s1 - s0, 1);
    if (g16 == 0) {
        float fe[8], fr[8];
#pragma unroll
        for (int i = 0; i < 8; i++) {
            fe[i] = tanhf(ae[i] * invd);
            fr[i] = tanhf(ar[i] * invd);
        }
        float* oe = out + (size_t)n * OD + 8 * li;
        float* orp = out + (size_t)n * OD + FDIM + 8 * li;
        *(float4*)oe = make_float4(fe[0], fe[1], fe[2], fe[3]);
        *(float4*)(oe + 4) = make_float4(fe[4], fe[5], fe[6], fe[7]);
        *(float4*)orp = make_float4(fr[0], fr[1], fr[2], fr[3]);
        *(float4*)(orp + 4) = make_float4(fr[4], fr[5], fr[6], fr[7]);
        _Float16* hh = &g_hh[0][n][0];
        f16x8 he, hr;
#pragma unroll
        for (int i = 0; i < 8; i++) { he[i] = (_Float16)fe[i]; hr[i] = (_Float16)fr[i]; }
        *(f16x8*)(hh + 8 * li) = he;
        *(f16x8*)(hh + 128 + 8 * li) = hr;
    }
}

// --- one message-passing layer, BOTH duals fused, 4 edges/wave ---
__global__ __launch_bounds__(256) void k_layer(float* buf, int layer) {
    int wave = threadIdx.x >> 6, lane = threadIdx.x & 63;
    int n = blockIdx.x * 4 + wave;
    if (n >= NN) return;
    int g16 = lane >> 4, li = lane & 15;
    int bo_e = (layer + 1) * FF;          // output cols, ent block
    int bo_r = FDIM + (layer + 1) * FF;   // output cols, rel block
    const float2* ew = g_ew + layer * NR;
    const _Float16* hs = &g_hh[layer][0][0];
    int s0 = g_rowptr[n], s1 = g_rowptr[n + 1];
    if (s1 == s0) {
        if (g16 == 0) {
            float* oe = buf + (size_t)n * OD + bo_e + 8 * li;
            float* orp = buf + (size_t)n * OD + bo_r + 8 * li;
            *(float4*)oe = make_float4(0.f, 0.f, 0.f, 0.f);
            *(float4*)(oe + 4) = make_float4(0.f, 0.f, 0.f, 0.f);
            *(float4*)orp = make_float4(0.f, 0.f, 0.f, 0.f);
            *(float4*)(orp + 4) = make_float4(0.f, 0.f, 0.f, 0.f);
            if (layer == 0) {
                _Float16* hh = &g_hh[1][n][0];
                f16x8 z = (f16x8)(_Float16)0.f;
                *(f16x8*)(hh + 8 * li) = z;
                *(f16x8*)(hh + 128 + 8 * li) = z;
            }
        }
        return;
    }
    float ae[8], ar[8];
#pragma unroll
    for (int i = 0; i < 8; i++) { ae[i] = 0.f; ar[i] = 0.f; }
    float wse = 0.f, wsr = 0.f;
    for (int idx = s0; idx < s1; idx += 4) {
        int e = idx + g16;
        bool act = e < s1;
        u32 pk = g_csr[act ? e : s0];
        int s = (int)(pk >> 16), r = (int)(pk & 0xFFFFu);
        const _Float16* hrow = hs + (size_t)s * 256;
        f16x8 hev = *(const f16x8*)(hrow + 8 * li);
        f16x8 hrv = *(const f16x8*)(hrow + 128 + 8 * li);
        const float* rp = g_relnorm + (size_t)r * FF + 8 * li;
        float4 rn0 = *(const float4*)rp;
        float4 rn1 = *(const float4*)(rp + 4);
        float rnv[8] = {rn0.x, rn0.y, rn0.z, rn0.w, rn1.x, rn1.y, rn1.z, rn1.w};
        float he[8], hr[8];
#pragma unroll
        for (int i = 0; i < 8; i++) { he[i] = (float)hev[i]; hr[i] = (float)hrv[i]; }
        float de = 0.f, dr = 0.f;
#pragma unroll
        for (int i = 0; i < 8; i++) {
            de = fmaf(he[i], rnv[i], de);
            dr = fmaf(hr[i], rnv[i], dr);
        }
        red16x2(de, dr);
        float2 wv = act ? ew[r] : make_float2(0.f, 0.f);
        wse += wv.x; wsr += wv.y;
        float te = -2.f * de, tr = -2.f * dr;
#pragma unroll
        for (int i = 0; i < 8; i++) {
            ae[i] = fmaf(wv.x, fmaf(te, rnv[i], he[i]), ae[i]);
            ar[i] = fmaf(wv.y, fmaf(tr, rnv[i], hr[i]), ar[i]);
        }
    }
#pragma unroll
    for (int mk = 16; mk < 64; mk <<= 1) {
#pragma unroll
        for (int i = 0; i < 8; i++) {
            ae[i] += __shfl_xor(ae[i], mk, 64);
            ar[i] += __shfl_xor(ar[i], mk, 64);
        }
        wse += __shfl_xor(wse, mk, 64);
        wsr += __shfl_xor(wsr, mk, 64);
    }
    float ive = 1.f / wse, ivr = 1.f / wsr;
    if (g16 == 0) {
        float fe[8], fr[8];
#pragma unroll
        for (int i = 0; i < 8; i++) {
            fe[i] = tanhf(ae[i] * ive);
            fr[i] = tanhf(ar[i] * ivr);
        }
        float* oe = buf + (size_t)n * OD + bo_e + 8 * li;
        float* orp = buf + (size_t)n * OD + bo_r + 8 * li;
        *(float4*)oe = make_float4(fe[0], fe[1], fe[2], fe[3]);
        *(float4*)(oe + 4) = make_float4(fe[4], fe[5], fe[6], fe[7]);
        *(float4*)orp = make_float4(fr[0], fr[1], fr[2], fr[3]);
        *(float4*)(orp + 4) = make_float4(fr[4], fr[5], fr[6], fr[7]);
        if (layer == 0) {
            _Float16* hh = &g_hh[1][n][0];
            f16x8 he16, hr16;
#pragma unroll
            for (int i = 0; i < 8; i++) { he16[i] = (_Float16)fe[i]; hr16[i] = (_Float16)fr[i]; }
            *(f16x8*)(hh + 8 * li) = he16;
            *(f16x8*)(hh + 128 + 8 * li) = hr16;
        }
    }
}

// --- k_pg v6: barrier-free wave-autonomous proxy-attention + gate ---
// Wave owns 16 nodes (n0w..n0w+15). Lane (c,kg): A-frags = row c,
// cols 32ks+8kg+j — lane-private. Per-wave LDS scratch only:
//   scrA (16x68 u32): att transpose (D-layout write -> A-layout read)
//   scrT (16x36 f32): pacc 32-col chunk transpose for pf build
// No __syncthreads anywhere.
__global__ __launch_bounds__(256, 2) void k_pg(
    float* out, const float* __restrict__ bias_e,
    const float* __restrict__ bias_r) {
    __shared__ __attribute__((aligned(16))) u32 scr[4][16 * SCRW + 16 * TSTR];  // 26.6 KB
    int tid = threadIdx.x;
    int lane = tid & 63, w = tid >> 6;
    int c = lane & 15, kg = lane >> 4;
    int dual = blockIdx.y;
    int n0w = blockIdx.x * 64 + w * 16;
    if (n0w >= NN) return;            // whole-wave exit; no barriers to violate
    int doff = dual * FDIM;
    const float* bias = dual ? bias_r : bias_e;
    const u16* wt_h = g_wt_hi + dual * (FDIM * FDIM);
    const u16* wt_l = g_wt_lo + dual * (FDIM * FDIM);
    const u16* pn_h = g_pxn_hi + dual * (PP * FDIM);
    const u16* pn_l = g_pxn_lo + dual * (PP * FDIM);
    const u16* pt_h = g_pxT_hi + dual * (FDIM * PP);
    const u16* pt_l = g_pxT_lo + dual * (FDIM * PP);
    u32* scrA = scr[w];
    float* scrT = (float*)(scr[w] + 16 * SCRW);
    const float* orow = out + (size_t)(n0w + c) * OD + doff;   // lane's node row

    // ---- phase A: logits (16 nodes x all 64 proxies) + invn ----
    float ss = 0.f;
    f32x4 lacc[4];
#pragma unroll
    for (int pt = 0; pt < 4; pt++) lacc[pt] = (f32x4){0.f, 0.f, 0.f, 0.f};
#pragma unroll
    for (int ks = 0; ks < 12; ks++) {
        int kb = 32 * ks + 8 * kg;
        float4 f0 = *(const float4*)(orow + kb);
        float4 f1 = *(const float4*)(orow + kb + 4);
        float fv[8] = {f0.x, f0.y, f0.z, f0.w, f1.x, f1.y, f1.z, f1.w};
        u32 pk[8];
#pragma unroll
        for (int j = 0; j < 8; j++) {
            ss = fmaf(fv[j], fv[j], ss);
            pk[j] = pack_bf(fv[j]);
        }
        bf16x8 ah, al;
        split_frag(pk, ah, al);
#pragma unroll
        for (int pt = 0; pt < 4; pt++) {
            bf16x8 bh = *(const bf16x8*)(pn_h + (16 * pt + c) * FDIM + kb);
            bf16x8 bl = *(const bf16x8*)(pn_l + (16 * pt + c) * FDIM + kb);
            lacc[pt] = __builtin_amdgcn_mfma_f32_16x16x32_bf16(ah, bh, lacc[pt], 0, 0, 0);
            lacc[pt] = __builtin_amdgcn_mfma_f32_16x16x32_bf16(al, bh, lacc[pt], 0, 0, 0);
            lacc[pt] = __builtin_amdgcn_mfma_f32_16x16x32_bf16(ah, bl, lacc[pt], 0, 0, 0);
        }
    }
    ss += __shfl_xor(ss, 16, 64);
    ss += __shfl_xor(ss, 32, 64);
    float invn = 1.f / fmaxf(sqrtf(ss), NEPS);   // lane holds invn for node c

    // ---- softmax over P=64, in register (no max-pass: logits are cosines) ----
    float ev[4][4], den[4] = {0.f, 0.f, 0.f, 0.f};
#pragma unroll
    for (int i = 0; i < 4; i++) {
        float ivi = __shfl(invn, 4 * kg + i, 64);   // invn of node 4kg+i
#pragma unroll
        for (int pt = 0; pt < 4; pt++) {
            float e = expf(lacc[pt][i] * ivi);
            ev[pt][i] = e;
            den[i] += e;
        }
    }
#pragma unroll
    for (int m = 1; m < 16; m <<= 1)
#pragma unroll
        for (int i = 0; i < 4; i++) den[i] += __shfl_xor(den[i], m, 64);
    // pack att -> scrA at [node 4kg+i][p 16pt+c]
#pragma unroll
    for (int i = 0; i < 4; i++) {
        float rd = 1.f / den[i];
#pragma unroll
        for (int pt = 0; pt < 4; pt++)
            scrA[(4 * kg + i) * SCRW + 16 * pt + c] = pack_bf(ev[pt][i] * rd);
    }
    // read att A-frags: [node c][p 8kg+j], [node c][p 32+8kg+j]
    bf16x8 aah0, aal0, aah1, aal1;
    load_afrag(scrA + c * SCRW + 8 * kg, aah0, aal0);
    load_afrag(scrA + c * SCRW + 32 + 8 * kg, aah1, aal1);

    // ---- phase B: pacc = att @ proxy (16 nodes x 384 f) ----
    f32x4 pacc[24];
#pragma unroll
    for (int t = 0; t < 24; t++) pacc[t] = (f32x4){0.f, 0.f, 0.f, 0.f};
#pragma unroll 2
    for (int t = 0; t < 24; t++) {
        const u16* bh0 = pt_h + (16 * t + c) * PP;
        const u16* bl0 = pt_l + (16 * t + c) * PP;
        bf16x8 b0h = *(const bf16x8*)(bh0 + 8 * kg);
        bf16x8 b0l = *(const bf16x8*)(bl0 + 8 * kg);
        bf16x8 b1h = *(const bf16x8*)(bh0 + 32 + 8 * kg);
        bf16x8 b1l = *(const bf16x8*)(bl0 + 32 + 8 * kg);
        pacc[t] = __builtin_amdgcn_mfma_f32_16x16x32_bf16(aah0, b0h, pacc[t], 0, 0, 0);
        pacc[t] = __builtin_amdgcn_mfma_f32_16x16x32_bf16(aal0, b0h, pacc[t], 0, 0, 0);
        pacc[t] = __builtin_amdgcn_mfma_f32_16x16x32_bf16(aah0, b0l, pacc[t], 0, 0, 0);
        pacc[t] = __builtin_amdgcn_mfma_f32_16x16x32_bf16(aah1, b1h, pacc[t], 0, 0, 0);
        pacc[t] = __builtin_amdgcn_mfma_f32_16x16x32_bf16(aal1, b1h, pacc[t], 0, 0, 0);
        pacc[t] = __builtin_amdgcn_mfma_f32_16x16x32_bf16(aah1, b1l, pacc[t], 0, 0, 0);
    }

    // ---- phase C: pf A-frags; per ks: transpose pacc chunk via scrT,
    //      re-read o from global (L3-hot), pf = o - paccT, pack ----
    bf16x8 pfh[12], pfl[12];
#pragma unroll
    for (int ks = 0; ks < 12; ks++) {
        // write pacc tiles 2ks, 2ks+1 (D-layout) into the 32-col chunk
#pragma unroll
        for (int u = 0; u < 2; u++) {
            int t = 2 * ks + u;
#pragma unroll
            for (int i = 0; i < 4; i++)
                scrT[(4 * kg + i) * TSTR + 16 * u + c] = pacc[t][i];
        }
        int kb = 32 * ks + 8 * kg;
        float4 o0 = *(const float4*)(orow + kb);
        float4 o1 = *(const float4*)(orow + kb + 4);
        float ofv[8] = {o0.x, o0.y, o0.z, o0.w, o1.x, o1.y, o1.z, o1.w};
        // read transposed chunk at A-coords [row c][local col 8kg+j]
        float4 p0 = *(const float4*)(scrT + c * TSTR + 8 * kg);
        float4 p1 = *(const float4*)(scrT + c * TSTR + 8 * kg + 4);
        float pfv[8] = {p0.x, p0.y, p0.z, p0.w, p1.x, p1.y, p1.z, p1.w};
        u32 pk[8];
#pragma unroll
        for (int j = 0; j < 8; j++) pk[j] = pack_bf(ofv[j] - pfv[j]);
        split_frag(pk, pfh[ks], pfl[ks]);
    }

    // ---- phase D: gate GEMM lin = pf @ W (16 nodes x 384 f') ----
    f32x4 lin[24];
#pragma unroll
    for (int t = 0; t < 24; t++) lin[t] = (f32x4){0.f, 0.f, 0.f, 0.f};
#pragma unroll
    for (int ks = 0; ks < 12; ks++) {
        int kb = 32 * ks + 8 * kg;
        bf16x8 ah = pfh[ks], al = pfl[ks];
#pragma unroll 4
        for (int t = 0; t < 24; t++) {
            bf16x8 bh = *(const bf16x8*)(wt_h + (16 * t + c) * FDIM + kb);
            bf16x8 bl = *(const bf16x8*)(wt_l + (16 * t + c) * FDIM + kb);
            lin[t] = __builtin_amdgcn_mfma_f32_16x16x32_bf16(ah, bh, lin[t], 0, 0, 0);
            lin[t] = __builtin_amdgcn_mfma_f32_16x16x32_bf16(al, bh, lin[t], 0, 0, 0);
            lin[t] = __builtin_amdgcn_mfma_f32_16x16x32_bf16(ah, bl, lin[t], 0, 0, 0);
        }
    }

    // ---- phase E: recompute pacc (att frags re-read from scrA — intact),
    //      then epilogue: out = ov - (1-gt)*pacc  (D-layout everywhere) ----
    load_afrag(scrA + c * SCRW + 8 * kg, aah0, aal0);
    load_afrag(scrA + c * SCRW + 32 + 8 * kg, aah1, aal1);
    f32x4 p2[24];
#pragma unroll
    for (int t = 0; t < 24; t++) p2[t] = (f32x4){0.f, 0.f, 0.f, 0.f};
#pragma unroll 2
    for (int t = 0; t < 24; t++) {
        const u16* bh0 = pt_h + (16 * t + c) * PP;
        const u16* bl0 = pt_l + (16 * t + c) * PP;
        bf16x8 b0h = *(const bf16x8*)(bh0 + 8 * kg);
        bf16x8 b0l = *(const bf16x8*)(bl0 + 8 * kg);
        bf16x8 b1h = *(const bf16x8*)(bh0 + 32 + 8 * kg);
        bf16x8 b1l = *(const bf16x8*)(bl0 + 32 + 8 * kg);
        p2[t] = __builtin_amdgcn_mfma_f32_16x16x32_bf16(aah0, b0h, p2[t], 0, 0, 0);
        p2[t] = __builtin_amdgcn_mfma_f32_16x16x32_bf16(aal0, b0h, p2[t], 0, 0, 0);
        p2[t] = __builtin_amdgcn_mfma_f32_16x16x32_bf16(aah0, b0l, p2[t], 0, 0, 0);
        p2[t] = __builtin_amdgcn_mfma_f32_16x16x32_bf16(aah1, b1h, p2[t], 0, 0, 0);
        p2[t] = __builtin_amdgcn_mfma_f32_16x16x32_bf16(aal1, b1h, p2[t], 0, 0, 0);
        p2[t] = __builtin_amdgcn_mfma_f32_16x16x32_bf16(aah1, b1l, p2[t], 0, 0, 0);
    }
#pragma unroll
    for (int t = 0; t < 24; t++) {
        float b = bias[16 * t + c];
#pragma unroll
        for (int i = 0; i < 4; i++) {
            float lv = lin[t][i] + b;
            float gt = 1.f / (1.f + expf(-lv));
            float* op = out + (size_t)(n0w + 4 * kg + i) * OD + doff + 16 * t + c;
            float ov = *op;
            // gt*ov + (1-gt)*(ov - p2) == ov - (1-gt)*p2
            *op = ov - (1.f - gt) * p2[t][i];
        }
    }
}

extern "C" void kernel_launch(void* const* d_in, const int* in_sizes, int n_in,
                              void* d_out, int out_size, void* d_ws, size_t ws_size,
                              hipStream_t stream) {
    const float* ent_emb = (const float*)d_in[0];
    const float* rel_emb = (const float*)d_in[1];
    const int* e_src     = (const int*)d_in[2];
    const int* e_dst     = (const int*)d_in[3];
    const int* e_rel     = (const int*)d_in[4];
    const float* attn_e  = (const float*)d_in[5];
    const float* gate_e  = (const float*)d_in[6];
    const float* proxy_e = (const float*)d_in[7];
    const float* bias_e  = (const float*)d_in[8];
    const float* attn_r  = (const float*)d_in[9];
    const float* gate_r  = (const float*)d_in[10];
    const float* proxy_r = (const float*)d_in[11];
    const float* bias_r  = (const float*)d_in[12];
    float* out = (float*)d_out;
    (void)d_ws; (void)ws_size; (void)in_sizes; (void)n_in; (void)out_size;

    k_zero<<<(NN + 255) / 256, 256, 0, stream>>>();
    k_prep_rel<<<NR / 4, 256, 0, stream>>>(rel_emb, attn_e, attn_r);
    k_prep_ent<<<(NN * FF / 8 + 255) / 256, 256, 0, stream>>>(ent_emb);
    k_prep_proxy<<<32, 256, 0, stream>>>(proxy_e, proxy_r);
    k_prep_wt<<<(2 * FDIM * FDIM + 255) / 256, 256, 0, stream>>>(gate_e, gate_r);
    k_count<<<(NE + 255) / 256, 256, 0, stream>>>(e_dst);
    k_scan1<<<NBLK, 1024, 0, stream>>>();
    k_scan2<<<1, 64, 0, stream>>>();
    k_scan3<<<NBLK, 1024, 0, stream>>>();
    k_fill<<<(NE + 255) / 256, 256, 0, stream>>>(e_src, e_dst, e_rel);
    k_init<<<NN / 4, 256, 0, stream>>>(rel_emb, out);
    k_layer<<<NN / 4, 256, 0, stream>>>(out, 0);
    k_layer<<<NN / 4, 256, 0, stream>>>(out, 1);
    k_pg<<<dim3((NN + 63) / 64, 2), 256, 0, stream>>>(out, bias_e, bias_r);
}